// Round 1
// 933.150 us; speedup vs baseline: 1.2878x; 1.2878x over previous
//
#include <hip/hip_runtime.h>

#define H 100
#define B 16
#define S 256
#define V 32000
#define NROW (B*S)   // 4096
#define KP 128       // K padded to 128 for 4x mfma_16x16x32

typedef __attribute__((ext_vector_type(8))) short short8;   // 8 bf16 = 4 VGPRs
typedef __attribute__((ext_vector_type(4))) float f32x4;

static __device__ __forceinline__ unsigned short f2bf(float f) {
    unsigned u = __float_as_uint(f);
    u += 0x7FFF + ((u >> 16) & 1);    // round-to-nearest-even
    return (unsigned short)(u >> 16);
}
static __device__ __forceinline__ unsigned pack2(float a, float b) {
    return (unsigned)f2bf(a) | ((unsigned)f2bf(b) << 16);
}

// ---------------------------------------------------------------------------
// K1: xpart[row][j] = emb[x[row]] @ W_ih[:,j] + b_ih[j] + b_hh[j]
// 16 rows per block; W_ih column held in registers (loaded once per block).
// Also zeroes sumexp (replaces the memset dispatch).
// ---------------------------------------------------------------------------
__global__ __launch_bounds__(128) void k_embed_xpart(
    const int* __restrict__ x, const float* __restrict__ emb,
    const float* __restrict__ Wih, const float* __restrict__ bih,
    const float* __restrict__ bhh, float* __restrict__ xpart,
    float* __restrict__ sumexp)
{
    int r0 = blockIdx.x * 16;          // grid 256 * 16 = 4096 rows
    int j = threadIdx.x;
    __shared__ int toks[16];
    __shared__ __align__(16) float e_s[16][100];
    if (j < 16) { toks[j] = x[r0 + j]; sumexp[r0 + j] = 0.f; }
    __syncthreads();
#pragma unroll
    for (int r = 0; r < 16; r++)
        if (j < H) e_s[r][j] = emb[toks[r] * H + j];
    float wv[H];
    if (j < H) {
#pragma unroll
        for (int k = 0; k < H; k++) wv[k] = Wih[k * H + j];   // coalesced over j
    }
    __syncthreads();
    if (j >= H) return;
    float bias = bih[j] + bhh[j];
    for (int r = 0; r < 16; r++) {
        const float4* e4 = (const float4*)e_s[r];
        float a0 = bias, a1 = 0.f, a2 = 0.f, a3 = 0.f;
#pragma unroll
        for (int kk = 0; kk < 25; kk++) {
            float4 ev = e4[kk];
            a0 = fmaf(ev.x, wv[4*kk+0], a0);
            a1 = fmaf(ev.y, wv[4*kk+1], a1);
            a2 = fmaf(ev.z, wv[4*kk+2], a2);
            a3 = fmaf(ev.w, wv[4*kk+3], a3);
        }
        xpart[(r0 + r) * H + j] = (a0 + a1) + (a2 + a3);
    }
}

// ---------------------------------------------------------------------------
// K2 (fused): blocks 0..124 transpose+cast Wfc -> WfcT [V][128] bf16;
// blocks 125..140 run the sequential RNN scan (one per batch element).
// The scan only occupies 16 CUs, so the transpose rides along for free.
// Scan accumulator chain broken into 4 partials (dep depth 100 -> 25).
// ---------------------------------------------------------------------------
__global__ __launch_bounds__(256) void k_wfcT_scan(
    const float* __restrict__ Wfc, unsigned short* __restrict__ WfcT,
    const float* __restrict__ xpart, const float* __restrict__ h0,
    const float* __restrict__ Whh, unsigned short* __restrict__ hsB,
    float* __restrict__ hlast)
{
    if (blockIdx.x < 125) {
        int v = blockIdx.x * 256 + threadIdx.x;   // 125*256 = 32000 exact
        float w[100];
#pragma unroll
        for (int k = 0; k < 100; k++) w[k] = Wfc[(long long)k * V + v];
        unsigned* dst = (unsigned*)(WfcT + (long long)v * KP);
#pragma unroll
        for (int q = 0; q < 12; q++) {
            uint4 o;
            o.x = pack2(w[q*8+0], w[q*8+1]);
            o.y = pack2(w[q*8+2], w[q*8+3]);
            o.z = pack2(w[q*8+4], w[q*8+5]);
            o.w = pack2(w[q*8+6], w[q*8+7]);
            *(uint4*)(dst + q*4) = o;
        }
        uint2 t;
        t.x = pack2(w[96], w[97]);
        t.y = pack2(w[98], w[99]);
        *(uint2*)(dst + 48) = t;
        *(uint2*)(dst + 50) = make_uint2(0,0);
        *(uint4*)(dst + 52) = make_uint4(0,0,0,0);
        *(uint4*)(dst + 56) = make_uint4(0,0,0,0);
        *(uint4*)(dst + 60) = make_uint4(0,0,0,0);
        return;
    }

    int b = blockIdx.x - 125;
    int j = threadIdx.x;
    __shared__ __align__(16) float hbuf[2][128];
    float wv[H];
    if (j < H) {
#pragma unroll
        for (int k = 0; k < H; k++) wv[k] = Whh[k * H + j];   // coalesced over j
        hbuf[0][j] = h0[b * H + j];
    }
    __syncthreads();
    float xp = (j < H) ? xpart[(b * S) * H + j] : 0.f;
    int p = 0;
    for (int t = 0; t < S; t++) {
        float hnew = 0.f;
        if (j < H) {
            const float4* h4 = (const float4*)hbuf[p];
            float a0 = xp, a1 = 0.f, a2 = 0.f, a3 = 0.f;
#pragma unroll
            for (int kk = 0; kk < 25; kk++) {
                float4 hv = h4[kk];
                a0 = fmaf(hv.x, wv[4*kk+0], a0);
                a1 = fmaf(hv.y, wv[4*kk+1], a1);
                a2 = fmaf(hv.z, wv[4*kk+2], a2);
                a3 = fmaf(hv.w, wv[4*kk+3], a3);
            }
            if (t + 1 < S) xp = xpart[(b * S + t + 1) * H + j];
            float acc = (a0 + a1) + (a2 + a3);
            float xc = fminf(fmaxf(acc, -15.f), 15.f);
            float e = __expf(2.f * xc);
            hnew = (e - 1.f) / (e + 1.f);
            hbuf[p ^ 1][j] = hnew;
        }
        if (j < KP) hsB[(b * S + t) * KP + j] = (j < H) ? f2bf(hnew) : (unsigned short)0;
        __syncthreads();
        p ^= 1;
    }
    if (j < H) hlast[b * H + j] = hbuf[p][j];
}

// ---------------------------------------------------------------------------
// K3: pass 1 — MFMA GEMM, per-row sum(exp(logit+bias)).
// Re-blocked: 128 rows/block (2 row-tiles of 16 per wave), 16 col-chunks of
// 2000. chunk = bid & 15 so XCD k (= bid & 7) only ever touches chunks
// {k, k+8} -> 1 MB of WfcT, L2-resident. B traffic halved vs old (2 row-
// tiles amortize each B fragment).
// ---------------------------------------------------------------------------
__global__ __launch_bounds__(256) void k_sumexp(
    const unsigned short* __restrict__ hsB, const unsigned short* __restrict__ WfcT,
    const float* __restrict__ bfc, float* __restrict__ sumexp)
{
    int bid = blockIdx.x;                       // grid 512 = 16 chunks * 32 rowtiles
    int lane = threadIdx.x & 63, w = threadIdx.x >> 6;
    int quad = lane >> 4, l15 = lane & 15;
    int r0 = (bid >> 4) * 128 + w * 32;
    int n0 = (bid & 15) * 2000;
    const short8* ap0 = (const short8*)(hsB + (long long)(r0 + l15) * KP + quad * 8);
    const short8* ap1 = (const short8*)(hsB + (long long)(r0 + 16 + l15) * KP + quad * 8);
    short8 a00 = ap0[0], a01 = ap0[4], a02 = ap0[8], a03 = ap0[12];
    short8 a10 = ap1[0], a11 = ap1[4], a12 = ap1[8], a13 = ap1[12];
    float p00=0.f,p01=0.f,p02=0.f,p03=0.f;
    float p10=0.f,p11=0.f,p12=0.f,p13=0.f;
    for (int nt = 0; nt < 125; nt++) {
        int col = n0 + nt * 16 + l15;
        const short8* bptr = (const short8*)(WfcT + (long long)col * KP + quad * 8);
        short8 b0 = bptr[0], b1 = bptr[4], b2 = bptr[8], b3 = bptr[12];
        f32x4 c0 = {0.f,0.f,0.f,0.f}, c1 = {0.f,0.f,0.f,0.f};
        c0 = __builtin_amdgcn_mfma_f32_16x16x32_bf16(a00, b0, c0, 0, 0, 0);
        c0 = __builtin_amdgcn_mfma_f32_16x16x32_bf16(a01, b1, c0, 0, 0, 0);
        c0 = __builtin_amdgcn_mfma_f32_16x16x32_bf16(a02, b2, c0, 0, 0, 0);
        c0 = __builtin_amdgcn_mfma_f32_16x16x32_bf16(a03, b3, c0, 0, 0, 0);
        c1 = __builtin_amdgcn_mfma_f32_16x16x32_bf16(a10, b0, c1, 0, 0, 0);
        c1 = __builtin_amdgcn_mfma_f32_16x16x32_bf16(a11, b1, c1, 0, 0, 0);
        c1 = __builtin_amdgcn_mfma_f32_16x16x32_bf16(a12, b2, c1, 0, 0, 0);
        c1 = __builtin_amdgcn_mfma_f32_16x16x32_bf16(a13, b3, c1, 0, 0, 0);
        float bias = bfc[col];
        p00 += __expf(c0[0] + bias); p01 += __expf(c0[1] + bias);
        p02 += __expf(c0[2] + bias); p03 += __expf(c0[3] + bias);
        p10 += __expf(c1[0] + bias); p11 += __expf(c1[1] + bias);
        p12 += __expf(c1[2] + bias); p13 += __expf(c1[3] + bias);
    }
#pragma unroll
    for (int m = 1; m <= 8; m <<= 1) {   // reduce over the 16 cols (lane&15)
        p00 += __shfl_xor(p00, m); p01 += __shfl_xor(p01, m);
        p02 += __shfl_xor(p02, m); p03 += __shfl_xor(p03, m);
        p10 += __shfl_xor(p10, m); p11 += __shfl_xor(p11, m);
        p12 += __shfl_xor(p12, m); p13 += __shfl_xor(p13, m);
    }
    if (l15 == 0) {
        int rr = r0 + quad * 4;
        atomicAdd(&sumexp[rr + 0], p00);
        atomicAdd(&sumexp[rr + 1], p01);
        atomicAdd(&sumexp[rr + 2], p02);
        atomicAdd(&sumexp[rr + 3], p03);
        atomicAdd(&sumexp[rr + 16], p10);
        atomicAdd(&sumexp[rr + 17], p11);
        atomicAdd(&sumexp[rr + 18], p12);
        atomicAdd(&sumexp[rr + 19], p13);
    }
}

// ---------------------------------------------------------------------------
// K4: pass 2 — MFMA GEMM, out = logit + bias - log(sumexp[row]).
// Re-blocked: 256 rows/block (4 row-tiles per wave) x 128-col chunks.
// bid = cc*16 + rt: the 16 row-blocks of a chunk are consecutive, so each
// XCD fetches each 32 KB B-chunk once. lse folded in (k_lse removed).
// B traffic: 2 GB -> 512 MB; writes (524 MB) become the bound.
// ---------------------------------------------------------------------------
__global__ __launch_bounds__(256) void k_out(
    const unsigned short* __restrict__ hsB, const unsigned short* __restrict__ WfcT,
    const float* __restrict__ bfc, const float* __restrict__ sumexp,
    float* __restrict__ out)
{
    int bid = blockIdx.x;                 // grid 4000 = 250 col-chunks * 16 row-blocks
    int cc = bid >> 4;                    // 0..249
    int rt = bid & 15;                    // 0..15
    int lane = threadIdx.x & 63, w = threadIdx.x >> 6;
    int quad = lane >> 4, l15 = lane & 15;
    int r0 = rt * 256 + w * 64;
    int n0 = cc * 128;
    short8 a[4][4];
#pragma unroll
    for (int i = 0; i < 4; i++) {
        const short8* ap = (const short8*)(hsB + (long long)(r0 + i * 16 + l15) * KP + quad * 8);
        a[i][0] = ap[0]; a[i][1] = ap[4]; a[i][2] = ap[8]; a[i][3] = ap[12];
    }
    float ls[4][4];
#pragma unroll
    for (int i = 0; i < 4; i++)
#pragma unroll
        for (int jj = 0; jj < 4; jj++)
            ls[i][jj] = __logf(sumexp[r0 + i * 16 + quad * 4 + jj]);
    long long base0 = (long long)(r0 + quad * 4) * V + n0 + l15;
#pragma unroll
    for (int nt = 0; nt < 8; nt++) {
        int col = n0 + nt * 16 + l15;
        const short8* bptr = (const short8*)(WfcT + (long long)col * KP + quad * 8);
        short8 b0 = bptr[0], b1 = bptr[4], b2 = bptr[8], b3 = bptr[12];
        float bias = bfc[col];
#pragma unroll
        for (int i = 0; i < 4; i++) {
            f32x4 c = {0.f,0.f,0.f,0.f};
            c = __builtin_amdgcn_mfma_f32_16x16x32_bf16(a[i][0], b0, c, 0, 0, 0);
            c = __builtin_amdgcn_mfma_f32_16x16x32_bf16(a[i][1], b1, c, 0, 0, 0);
            c = __builtin_amdgcn_mfma_f32_16x16x32_bf16(a[i][2], b2, c, 0, 0, 0);
            c = __builtin_amdgcn_mfma_f32_16x16x32_bf16(a[i][3], b3, c, 0, 0, 0);
            long long rb = base0 + (long long)i * 16 * V + nt * 16;
            out[rb]           = c[0] + bias - ls[i][0];
            out[rb + V]       = c[1] + bias - ls[i][1];
            out[rb + 2LL * V] = c[2] + bias - ls[i][2];
            out[rb + 3LL * V] = c[3] + bias - ls[i][3];
        }
    }
}

extern "C" void kernel_launch(void* const* d_in, const int* in_sizes, int n_in,
                              void* d_out, int out_size, void* d_ws, size_t ws_size,
                              hipStream_t stream)
{
    const int*   x    = (const int*)d_in[0];
    const float* h0   = (const float*)d_in[1];
    const float* emb  = (const float*)d_in[2];
    const float* Wih  = (const float*)d_in[3];
    const float* Whh  = (const float*)d_in[4];
    const float* bih  = (const float*)d_in[5];
    const float* bhh  = (const float*)d_in[6];
    const float* Wfc  = (const float*)d_in[7];
    const float* bfc  = (const float*)d_in[8];

    float* out   = (float*)d_out;
    float* hlast = out + (long long)NROW * V;

    float* xpart  = (float*)d_ws;                              // 409600 f32
    float* sumexp = xpart + NROW * H;                          // 4096 f32
    unsigned short* WfcT = (unsigned short*)(sumexp + NROW);   // V*128 bf16 = 8.192 MB
    unsigned short* hsB  = WfcT + (long long)V * KP;           // NROW*128 bf16 = 1.05 MB

    k_embed_xpart<<<256, 128, 0, stream>>>(x, emb, Wih, bih, bhh, xpart, sumexp);
    k_wfcT_scan<<<141, 256, 0, stream>>>(Wfc, WfcT, xpart, h0, Whh, hsB, hlast);
    k_sumexp<<<512, 256, 0, stream>>>(hsB, WfcT, bfc, sumexp);
    k_out<<<4000, 256, 0, stream>>>(hsB, WfcT, bfc, sumexp, out);
}

// Round 2
// 862.392 us; speedup vs baseline: 1.3935x; 1.0820x over previous
//
#include <hip/hip_runtime.h>

#define H 100
#define B 16
#define S 256
#define V 32000
#define NROW (B*S)   // 4096
#define KP 128       // K padded to 128 for 4x mfma_16x16x32

typedef __attribute__((ext_vector_type(8))) short short8;   // 8 bf16 = 4 VGPRs
typedef __attribute__((ext_vector_type(4))) float f32x4;

static __device__ __forceinline__ unsigned short f2bf(float f) {
    unsigned u = __float_as_uint(f);
    u += 0x7FFF + ((u >> 16) & 1);    // round-to-nearest-even
    return (unsigned short)(u >> 16);
}
static __device__ __forceinline__ unsigned pack2(float a, float b) {
    return (unsigned)f2bf(a) | ((unsigned)f2bf(b) << 16);
}

// ---------------------------------------------------------------------------
// Shared helper: stage a 128-col x 256-byte B tile of WfcT into LDS (32 KB),
// XOR-pre-swizzled at the SOURCE so the swizzled ds_read_b128 fragment reads
// below are bank-balanced (rule: swizzle both sides or neither).
// LDS unit u (16B) holds global tile unit u ^ ((u>>4)&7)  (col preserved,
// 16B-slot XORed with col&7).
// ---------------------------------------------------------------------------
static __device__ __forceinline__ void stage_B128(
    const unsigned short* __restrict__ WfcT, int n0,
    unsigned short* Bs, int tid)
{
    const uint4* src = (const uint4*)(WfcT + (long long)n0 * KP);  // 2048 units
    uint4* dst = (uint4*)Bs;
#pragma unroll
    for (int k = 0; k < 8; k++) {
        int u = k * 256 + tid;
        int us = u ^ ((u >> 4) & 7);
        dst[u] = src[us];
    }
}
// Swizzled fragment read: B shorts col*128 + slot*8 .. +8, slot = quad + 4*s
static __device__ __forceinline__ short8 bfrag(
    const unsigned short* Bs, int nt, int l15, int slot)
{
    return *(const short8*)(Bs + nt * 2048 + l15 * 128 + ((slot ^ (l15 & 7)) * 8));
}

// ---------------------------------------------------------------------------
// K1: xpart[row][j] = emb[x[row]] @ W_ih[:,j] + b_ih[j] + b_hh[j]
// 16 rows per block; W_ih column held in registers. Also zeroes sumexp.
// ---------------------------------------------------------------------------
__global__ __launch_bounds__(128) void k_embed_xpart(
    const int* __restrict__ x, const float* __restrict__ emb,
    const float* __restrict__ Wih, const float* __restrict__ bih,
    const float* __restrict__ bhh, float* __restrict__ xpart,
    float* __restrict__ sumexp)
{
    int r0 = blockIdx.x * 16;          // grid 256 * 16 = 4096 rows
    int j = threadIdx.x;
    __shared__ int toks[16];
    __shared__ __align__(16) float e_s[16][100];
    if (j < 16) { toks[j] = x[r0 + j]; sumexp[r0 + j] = 0.f; }
    __syncthreads();
#pragma unroll
    for (int r = 0; r < 16; r++)
        if (j < H) e_s[r][j] = emb[toks[r] * H + j];
    float wv[H];
    if (j < H) {
#pragma unroll
        for (int k = 0; k < H; k++) wv[k] = Wih[k * H + j];   // coalesced over j
    }
    __syncthreads();
    if (j >= H) return;
    float bias = bih[j] + bhh[j];
    for (int r = 0; r < 16; r++) {
        const float4* e4 = (const float4*)e_s[r];
        float a0 = bias, a1 = 0.f, a2 = 0.f, a3 = 0.f;
#pragma unroll
        for (int kk = 0; kk < 25; kk++) {
            float4 ev = e4[kk];
            a0 = fmaf(ev.x, wv[4*kk+0], a0);
            a1 = fmaf(ev.y, wv[4*kk+1], a1);
            a2 = fmaf(ev.z, wv[4*kk+2], a2);
            a3 = fmaf(ev.w, wv[4*kk+3], a3);
        }
        xpart[(r0 + r) * H + j] = (a0 + a1) + (a2 + a3);
    }
}

// ---------------------------------------------------------------------------
// K2 (fused): blocks 0..124 transpose+cast Wfc -> WfcT [V][128] bf16;
// blocks 125..140 run the sequential RNN scan (one per batch element).
// ---------------------------------------------------------------------------
__global__ __launch_bounds__(256) void k_wfcT_scan(
    const float* __restrict__ Wfc, unsigned short* __restrict__ WfcT,
    const float* __restrict__ xpart, const float* __restrict__ h0,
    const float* __restrict__ Whh, unsigned short* __restrict__ hsB,
    float* __restrict__ hlast)
{
    if (blockIdx.x < 125) {
        int v = blockIdx.x * 256 + threadIdx.x;   // 125*256 = 32000 exact
        float w[100];
#pragma unroll
        for (int k = 0; k < 100; k++) w[k] = Wfc[(long long)k * V + v];
        unsigned* dst = (unsigned*)(WfcT + (long long)v * KP);
#pragma unroll
        for (int q = 0; q < 12; q++) {
            uint4 o;
            o.x = pack2(w[q*8+0], w[q*8+1]);
            o.y = pack2(w[q*8+2], w[q*8+3]);
            o.z = pack2(w[q*8+4], w[q*8+5]);
            o.w = pack2(w[q*8+6], w[q*8+7]);
            *(uint4*)(dst + q*4) = o;
        }
        uint2 t;
        t.x = pack2(w[96], w[97]);
        t.y = pack2(w[98], w[99]);
        *(uint2*)(dst + 48) = t;
        *(uint2*)(dst + 50) = make_uint2(0,0);
        *(uint4*)(dst + 52) = make_uint4(0,0,0,0);
        *(uint4*)(dst + 56) = make_uint4(0,0,0,0);
        *(uint4*)(dst + 60) = make_uint4(0,0,0,0);
        return;
    }

    int b = blockIdx.x - 125;
    int j = threadIdx.x;
    __shared__ __align__(16) float hbuf[2][128];
    float wv[H];
    if (j < H) {
#pragma unroll
        for (int k = 0; k < H; k++) wv[k] = Whh[k * H + j];   // coalesced over j
        hbuf[0][j] = h0[b * H + j];
    }
    __syncthreads();
    float xp = (j < H) ? xpart[(b * S) * H + j] : 0.f;
    int p = 0;
    for (int t = 0; t < S; t++) {
        float hnew = 0.f;
        if (j < H) {
            const float4* h4 = (const float4*)hbuf[p];
            float a0 = xp, a1 = 0.f, a2 = 0.f, a3 = 0.f;
#pragma unroll
            for (int kk = 0; kk < 25; kk++) {
                float4 hv = h4[kk];
                a0 = fmaf(hv.x, wv[4*kk+0], a0);
                a1 = fmaf(hv.y, wv[4*kk+1], a1);
                a2 = fmaf(hv.z, wv[4*kk+2], a2);
                a3 = fmaf(hv.w, wv[4*kk+3], a3);
            }
            if (t + 1 < S) xp = xpart[(b * S + t + 1) * H + j];
            float acc = (a0 + a1) + (a2 + a3);
            float xc = fminf(fmaxf(acc, -15.f), 15.f);
            float e = __expf(2.f * xc);
            hnew = (e - 1.f) / (e + 1.f);
            hbuf[p ^ 1][j] = hnew;
        }
        if (j < KP) hsB[(b * S + t) * KP + j] = (j < H) ? f2bf(hnew) : (unsigned short)0;
        __syncthreads();
        p ^= 1;
    }
    if (j < H) hlast[b * H + j] = hbuf[p][j];
}

// ---------------------------------------------------------------------------
// K3: pass 1 — MFMA GEMM, per-row sum(exp(logit+bias)).
// 128 rows x 128 cols per block; grid 8000 = 250 col-chunks * 32 row-blocks
// (~16-20 waves/CU). B tile staged ONCE in LDS, shared by all 4 waves
// (L2 B-traffic 1 GB -> 256 MB); consecutive bids share cc so each XCD's
// L2 fetch of a tile is amortized across its row-blocks.
// ---------------------------------------------------------------------------
__global__ __launch_bounds__(256) void k_sumexp(
    const unsigned short* __restrict__ hsB, const unsigned short* __restrict__ WfcT,
    const float* __restrict__ bfc, float* __restrict__ sumexp)
{
    __shared__ __align__(16) unsigned short Bs[128 * KP];   // 32 KB
    int bid = blockIdx.x;
    int cc = bid >> 5, rt = bid & 31;
    int tid = threadIdx.x;
    int lane = tid & 63, w = tid >> 6;
    int quad = lane >> 4, l15 = lane & 15;
    int n0 = cc * 128;
    int r0 = rt * 128 + w * 32;

    stage_B128(WfcT, n0, Bs, tid);

    const short8* ap0 = (const short8*)(hsB + (long long)(r0 + l15) * KP + quad * 8);
    const short8* ap1 = (const short8*)(hsB + (long long)(r0 + 16 + l15) * KP + quad * 8);
    short8 a00 = ap0[0], a01 = ap0[4], a02 = ap0[8], a03 = ap0[12];
    short8 a10 = ap1[0], a11 = ap1[4], a12 = ap1[8], a13 = ap1[12];
    float p00=0.f,p01=0.f,p02=0.f,p03=0.f;
    float p10=0.f,p11=0.f,p12=0.f,p13=0.f;
    __syncthreads();
#pragma unroll
    for (int nt = 0; nt < 8; nt++) {
        short8 b0 = bfrag(Bs, nt, l15, quad);
        short8 b1 = bfrag(Bs, nt, l15, quad + 4);
        short8 b2 = bfrag(Bs, nt, l15, quad + 8);
        short8 b3 = bfrag(Bs, nt, l15, quad + 12);
        f32x4 c0 = {0.f,0.f,0.f,0.f}, c1 = {0.f,0.f,0.f,0.f};
        c0 = __builtin_amdgcn_mfma_f32_16x16x32_bf16(a00, b0, c0, 0, 0, 0);
        c0 = __builtin_amdgcn_mfma_f32_16x16x32_bf16(a01, b1, c0, 0, 0, 0);
        c0 = __builtin_amdgcn_mfma_f32_16x16x32_bf16(a02, b2, c0, 0, 0, 0);
        c0 = __builtin_amdgcn_mfma_f32_16x16x32_bf16(a03, b3, c0, 0, 0, 0);
        c1 = __builtin_amdgcn_mfma_f32_16x16x32_bf16(a10, b0, c1, 0, 0, 0);
        c1 = __builtin_amdgcn_mfma_f32_16x16x32_bf16(a11, b1, c1, 0, 0, 0);
        c1 = __builtin_amdgcn_mfma_f32_16x16x32_bf16(a12, b2, c1, 0, 0, 0);
        c1 = __builtin_amdgcn_mfma_f32_16x16x32_bf16(a13, b3, c1, 0, 0, 0);
        float bias = bfc[n0 + nt * 16 + l15];
        p00 += __expf(c0[0] + bias); p01 += __expf(c0[1] + bias);
        p02 += __expf(c0[2] + bias); p03 += __expf(c0[3] + bias);
        p10 += __expf(c1[0] + bias); p11 += __expf(c1[1] + bias);
        p12 += __expf(c1[2] + bias); p13 += __expf(c1[3] + bias);
    }
#pragma unroll
    for (int m = 1; m <= 8; m <<= 1) {   // reduce over the 16 cols (lane&15)
        p00 += __shfl_xor(p00, m); p01 += __shfl_xor(p01, m);
        p02 += __shfl_xor(p02, m); p03 += __shfl_xor(p03, m);
        p10 += __shfl_xor(p10, m); p11 += __shfl_xor(p11, m);
        p12 += __shfl_xor(p12, m); p13 += __shfl_xor(p13, m);
    }
    if (l15 == 0) {
        int rr = r0 + quad * 4;
        atomicAdd(&sumexp[rr + 0], p00);
        atomicAdd(&sumexp[rr + 1], p01);
        atomicAdd(&sumexp[rr + 2], p02);
        atomicAdd(&sumexp[rr + 3], p03);
        atomicAdd(&sumexp[rr + 16], p10);
        atomicAdd(&sumexp[rr + 17], p11);
        atomicAdd(&sumexp[rr + 18], p12);
        atomicAdd(&sumexp[rr + 19], p13);
    }
}

// ---------------------------------------------------------------------------
// K4: pass 2 — MFMA GEMM, out = logit + bias - log(sumexp[row]).
// 256 rows x 128 cols per block; grid 4000 = 250 col-chunks * 16 row-blocks.
// B tile staged once in LDS (L2 B-traffic 512 -> 128 MB); non-temporal
// output stores keep the 524 MB stream from evicting WfcT/hsB in L2.
// ---------------------------------------------------------------------------
__global__ __launch_bounds__(256) void k_out(
    const unsigned short* __restrict__ hsB, const unsigned short* __restrict__ WfcT,
    const float* __restrict__ bfc, const float* __restrict__ sumexp,
    float* __restrict__ out)
{
    __shared__ __align__(16) unsigned short Bs[128 * KP];   // 32 KB
    int bid = blockIdx.x;                 // 4000 = 250 col-chunks * 16 row-blocks
    int cc = bid >> 4;                    // 0..249
    int rt = bid & 15;                    // 0..15
    int tid = threadIdx.x;
    int lane = tid & 63, w = tid >> 6;
    int quad = lane >> 4, l15 = lane & 15;
    int r0 = rt * 256 + w * 64;
    int n0 = cc * 128;

    stage_B128(WfcT, n0, Bs, tid);

    short8 a[4][4];
#pragma unroll
    for (int i = 0; i < 4; i++) {
        const short8* ap = (const short8*)(hsB + (long long)(r0 + i * 16 + l15) * KP + quad * 8);
        a[i][0] = ap[0]; a[i][1] = ap[4]; a[i][2] = ap[8]; a[i][3] = ap[12];
    }
    float ls[4][4];
#pragma unroll
    for (int i = 0; i < 4; i++)
#pragma unroll
        for (int jj = 0; jj < 4; jj++)
            ls[i][jj] = __logf(sumexp[r0 + i * 16 + quad * 4 + jj]);
    __syncthreads();

    long long base0 = (long long)(r0 + quad * 4) * V + n0 + l15;
#pragma unroll
    for (int nt = 0; nt < 8; nt++) {
        short8 b0 = bfrag(Bs, nt, l15, quad);
        short8 b1 = bfrag(Bs, nt, l15, quad + 4);
        short8 b2 = bfrag(Bs, nt, l15, quad + 8);
        short8 b3 = bfrag(Bs, nt, l15, quad + 12);
        float bias = bfc[n0 + nt * 16 + l15];
#pragma unroll
        for (int i = 0; i < 4; i++) {
            f32x4 c = {0.f,0.f,0.f,0.f};
            c = __builtin_amdgcn_mfma_f32_16x16x32_bf16(a[i][0], b0, c, 0, 0, 0);
            c = __builtin_amdgcn_mfma_f32_16x16x32_bf16(a[i][1], b1, c, 0, 0, 0);
            c = __builtin_amdgcn_mfma_f32_16x16x32_bf16(a[i][2], b2, c, 0, 0, 0);
            c = __builtin_amdgcn_mfma_f32_16x16x32_bf16(a[i][3], b3, c, 0, 0, 0);
            long long rb = base0 + (long long)i * 16 * V + nt * 16;
            __builtin_nontemporal_store(c[0] + bias - ls[i][0], &out[rb]);
            __builtin_nontemporal_store(c[1] + bias - ls[i][1], &out[rb + V]);
            __builtin_nontemporal_store(c[2] + bias - ls[i][2], &out[rb + 2LL * V]);
            __builtin_nontemporal_store(c[3] + bias - ls[i][3], &out[rb + 3LL * V]);
        }
    }
}

extern "C" void kernel_launch(void* const* d_in, const int* in_sizes, int n_in,
                              void* d_out, int out_size, void* d_ws, size_t ws_size,
                              hipStream_t stream)
{
    const int*   x    = (const int*)d_in[0];
    const float* h0   = (const float*)d_in[1];
    const float* emb  = (const float*)d_in[2];
    const float* Wih  = (const float*)d_in[3];
    const float* Whh  = (const float*)d_in[4];
    const float* bih  = (const float*)d_in[5];
    const float* bhh  = (const float*)d_in[6];
    const float* Wfc  = (const float*)d_in[7];
    const float* bfc  = (const float*)d_in[8];

    float* out   = (float*)d_out;
    float* hlast = out + (long long)NROW * V;

    float* xpart  = (float*)d_ws;                              // 409600 f32
    float* sumexp = xpart + NROW * H;                          // 4096 f32
    unsigned short* WfcT = (unsigned short*)(sumexp + NROW);   // V*128 bf16 = 8.192 MB
    unsigned short* hsB  = WfcT + (long long)V * KP;           // NROW*128 bf16 = 1.05 MB

    k_embed_xpart<<<256, 128, 0, stream>>>(x, emb, Wih, bih, bhh, xpart, sumexp);
    k_wfcT_scan<<<141, 256, 0, stream>>>(Wfc, WfcT, xpart, h0, Whh, hsB, hlast);
    k_sumexp<<<8000, 256, 0, stream>>>(hsB, WfcT, bfc, sumexp);
    k_out<<<4000, 256, 0, stream>>>(hsB, WfcT, bfc, sumexp, out);
}